// Round 11
// baseline (578.248 us; speedup 1.0000x reference)
//
#include <hip/hip_runtime.h>

#define BB 512
#define SS 256
#define HH 128
#define NC 10

typedef float v2f __attribute__((ext_vector_type(2)));

// v_pk_fma_f32 forced via asm ("v" constraints = arch VGPR operands).
__device__ __forceinline__ v2f pkmul(v2f a, v2f b) {
    v2f d;
    asm("v_pk_mul_f32 %0, %1, %2" : "=v"(d) : "v"(a), "v"(b));
    return d;
}
__device__ __forceinline__ v2f pkfma(v2f a, v2f b, v2f c) {
    v2f d;
    asm("v_pk_fma_f32 %0, %1, %2, %3" : "=v"(d) : "v"(a), "v"(b), "v"(c));
    return d;
}

// acc + (give from lane selected by DPP ctrl)
template<int CTRL>
__device__ __forceinline__ float dppadd(float acc, float give) {
    int t = __builtin_amdgcn_update_dpp(0, __float_as_int(give), CTRL, 0xF, 0xF, true);
    return acc + __int_as_float(t);
}

// cndmask-free reduce-scatter over the 16-lane group (verified).
__device__ __forceinline__ float red_scatter(const float v[8], int r) {
    float s0 = dppadd<0xB1>(v[0], v[1]);    // xor1
    float s2 = dppadd<0xB1>(v[2], v[3]);
    float s4 = dppadd<0xB1>(v[4], v[5]);
    float s6 = dppadd<0xB1>(v[6], v[7]);
    s0 = dppadd<0x4E>(s0, s2);              // xor2
    s4 = dppadd<0x4E>(s4, s6);
    {   // xor4 via row_ror 4 / 12
        int t1 = __builtin_amdgcn_update_dpp(0, __float_as_int(s4), 0x124, 0xF, 0xF, true);
        int t2 = __builtin_amdgcn_update_dpp(0, __float_as_int(s4), 0x12C, 0xF, 0xF, true);
        s0 += __int_as_float((r & 4) ? t2 : t1);
    }
    s0 = dppadd<0x128>(s0, s0);             // xor8 (row_ror:8)
    return s0;
}

// Barrier without the compiler's vmcnt(0) drain (LDS-visibility only).
__device__ __forceinline__ void barrier_nodrain() {
    asm volatile("s_waitcnt lgkmcnt(0)\n\ts_barrier" ::: "memory");
}

__device__ __forceinline__ float tanh_fast(float z) {
    const float e = __expf(2.f * z);
    return 1.f - 2.f * __builtin_amdgcn_rcpf(1.f + e);
}

// ---- named weight registers. R11: re-pinned EVERY loop iteration
// (KEEPALIVE) so the register allocator cannot rematerialize the weight
// loads from L2 inside the loop — the R2..R10 counters (VGPR=96 < 128
// weight floats, zero scratch, zero extra FETCH: weights are L2-resident
// so remat reloads are invisible in FETCH_SIZE) say per-step L2 reload
// streaming is the hidden cost. A value redefined by asm each iteration
// must stay live in arch VGPRs. Budget: 128 wt + ~75 state < 256. ----
#define WDECL(i) v2f w##i##_0, w##i##_1, w##i##_2, w##i##_3, \
                     w##i##_4, w##i##_5, w##i##_6, w##i##_7;
#define WLOADX(i) { const v2f* p_ = (const v2f*)(wa + (size_t)(8 * j + ((i) ^ g7)) * HH + 8 * r); \
    w##i##_0 = p_[0]; w##i##_1 = p_[1]; w##i##_2 = p_[2]; w##i##_3 = p_[3]; }
#define WLOADY(i) { const v2f* p_ = (const v2f*)(wb + (size_t)(8 * j + ((i) ^ g7)) * HH + 8 * r); \
    w##i##_4 = p_[0]; w##i##_5 = p_[1]; w##i##_6 = p_[2]; w##i##_7 = p_[3]; }
#define WZEROY(i) { w##i##_4 = (v2f)0.f; w##i##_5 = (v2f)0.f; \
                    w##i##_6 = (v2f)0.f; w##i##_7 = (v2f)0.f; }
#define KEEPX(i) asm volatile("" : "+v"(w##i##_0), "+v"(w##i##_1), \
                                   "+v"(w##i##_2), "+v"(w##i##_3));
#define KEEPY(i) asm volatile("" : "+v"(w##i##_4), "+v"(w##i##_5), \
                                   "+v"(w##i##_6), "+v"(w##i##_7));
// K=128 MAC slot (x-half only)
#define MAC4(i, x0, x1, x2, x3, d) { v2f a_ = pkmul(x0, w##i##_0);       \
    a_ = pkfma(x1, w##i##_1, a_); a_ = pkfma(x2, w##i##_2, a_);          \
    a_ = pkfma(x3, w##i##_3, a_); d = a_.x + a_.y; }
// K=256 MAC slot (x-half + y-half)
#define MAC8(i, x0, x1, x2, x3, y0, y1, y2, y3, d) { v2f a_ = pkmul(x0, w##i##_0); \
    a_ = pkfma(x1, w##i##_1, a_); a_ = pkfma(x2, w##i##_2, a_);                    \
    a_ = pkfma(x3, w##i##_3, a_); a_ = pkfma(y0, w##i##_4, a_);                    \
    a_ = pkfma(y1, w##i##_5, a_); a_ = pkfma(y2, w##i##_6, a_);                    \
    a_ = pkfma(y3, w##i##_7, a_); d = a_.x + a_.y; }
#define FORSLOT(M) M(0) M(1) M(2) M(3) M(4) M(5) M(6) M(7)

// =====================================================================
// proj_k: out[m][j] = sum_d A[m][d] * W[j][d]   (NO bias — scans add it)
// Layer 0 input projection only (K=28).  (Proven kernel, unchanged.)
// =====================================================================
template<int K>
__global__ __launch_bounds__(256, 1)
void proj_k(const float* __restrict__ A, const float* __restrict__ W,
            float* __restrict__ out)
{
    constexpr int AS = ((K + 31) / 32) * 32 + 4;
    constexpr int KQ = K / 4;
    constexpr int KCW = (K < 32) ? K : 32;
    constexpr int WQ = KCW / 4;
    const int tid = threadIdx.x;
    const int tx = tid & 15;
    const int ty = tid >> 4;
    const size_t m0 = (size_t)blockIdx.x * 64;

    __shared__ float Arm[64 * AS];
    __shared__ float Wst[128 * 36];

    for (int idx = tid; idx < 64 * KQ; idx += 256) {
        const int row = idx / KQ, kq = idx % KQ;
        const float4 v = *(const float4*)(A + (m0 + row) * K + 4 * kq);
        *(float4*)(&Arm[row * AS + 4 * kq]) = v;
    }

    float acc[4][8];
    #pragma unroll
    for (int c = 0; c < 8; ++c)
        #pragma unroll
        for (int r = 0; r < 4; ++r) acc[r][c] = 0.f;

    #pragma unroll 1
    for (int kc = 0; kc < K; kc += KCW) {
        __syncthreads();
        for (int idx = tid; idx < 128 * WQ; idx += 256) {
            const int col = idx / WQ, q = idx % WQ;
            const float4 v = *(const float4*)(W + (size_t)col * K + kc + 4 * q);
            *(float4*)(&Wst[col * 36 + 4 * q]) = v;
        }
        __syncthreads();
        #pragma unroll 2
        for (int q = 0; q < WQ; ++q) {
            float4 av[4];
            #pragma unroll
            for (int r = 0; r < 4; ++r)
                av[r] = *(const float4*)(&Arm[(ty + 16 * r) * AS + kc + 4 * q]);
            #pragma unroll
            for (int c = 0; c < 8; ++c) {
                const float4 wv = *(const float4*)(&Wst[(tx + 16 * c) * 36 + 4 * q]);
                #pragma unroll
                for (int r = 0; r < 4; ++r)
                    acc[r][c] += av[r].x * wv.x + av[r].y * wv.y
                               + av[r].z * wv.z + av[r].w * wv.w;
            }
        }
    }

    #pragma unroll
    for (int r = 0; r < 4; ++r)
        #pragma unroll
        for (int c = 0; c < 8; ++c)
            out[(m0 + ty + 16 * r) * HH + tx + 16 * c] = acc[r][c];
}

// =====================================================================
// scan_fuse<PAIR> (R11 = R7 structure + pk MACs + per-iteration weight
// register pinning): TWO stacked layers via combined-K recurrence, 2
// batches per block, 512 threads = role0 + role1.
//   PAIR=0: role0 = layer0 (staged xw0 + K=128 W_hh0);
//           role1 = layer1 (K=256), writes h1 rows to buf (plain fp32).
//   PAIR=1: role0 = layer2 (K=256, x-half = STAGED h1 rows);
//           role1 = layer3 (K=256), final h -> hfin.
// In-place: row X stage-read at T=X-8, h1-written at T=X+1.
// =====================================================================
template<int PAIR>
__global__ __attribute__((amdgpu_flat_work_group_size(512, 512),
                          amdgpu_waves_per_eu(2, 2)))
void scan_fuse(float* __restrict__ buf, float* __restrict__ hfin,
               const float* __restrict__ w_r0_a, const float* __restrict__ w_r0_b,
               const float* __restrict__ w_r1_a, const float* __restrict__ w_r1_b,
               const float* __restrict__ b0_ih, const float* __restrict__ b0_hh,
               const float* __restrict__ b1_ih, const float* __restrict__ b1_hh)
{
    const int blk  = blockIdx.x;
    const int tid  = threadIdx.x;
    const int role = tid >> 8;       // 0 = layer A, 1 = layer B (combined-K)
    const int t256 = tid & 255;
    const int j   = t256 >> 4;       // col group: cols 8j..8j+7
    const int r   = t256 & 15;       // k-chunk [8r, 8r+8)
    const int g7  = r & 7;
    const int cc  = 8 * j + g7;      // column this lane finalizes
    const int wsw = 12 * j + g7;     // swizzled word for cc

    float* const rowA = buf + (size_t)(2 * blk) * SS * HH;
    float* const rowB = rowA + (size_t)SS * HH;
    const float bias = role ? (b1_ih[cc] + b1_hh[cc]) : (b0_ih[cc] + b0_hh[cc]);

    // permuted weights: slot i = column 8j + (i^g7); _0.._3 = x-half
    // (W_ih or W_hh0), _4.._7 = y-half (W_hh) for combined-K roles.
    const float* wa = role ? w_r1_a : w_r0_a;
    const float* wb = role ? w_r1_b : w_r0_b;
    FORSLOT(WDECL)
    FORSLOT(WLOADX)
    if (PAIR == 1 || role == 1) { FORSLOT(WLOADY) }
    else                        { FORSLOT(WZEROY) }

    __shared__ float hsw[2][2][2][192];   // [layer][batch][dbuf][192], swizzled
    __shared__ float stg[2][8][2][192];   // [chunk][step][batch][192], swizzled

    for (int i = tid; i < 2 * 2 * 2 * 192; i += 512) ((float*)hsw)[i] = 0.f;

    const int st  = t256 >> 5;            // staging: step-in-chunk
    const int m32 = t256 & 31;            // staging: float4 index in row
    const int spw = 12 * (m32 >> 1) + 4 * (m32 & 1);  // swizzled float4 word
    if (role == 0) {                      // stage rows 0..7 (xw0 or h1)
        const float4 vA = *(const float4*)(rowA + (size_t)st * HH + 4 * m32);
        const float4 vB = *(const float4*)(rowB + (size_t)st * HH + 4 * m32);
        *(float4*)(&stg[0][st][0][spw]) = vA;
        *(float4*)(&stg[0][st][1][spw]) = vB;
    }
    __syncthreads();

    for (int T = 0; T <= SS; ++T) {
        const int cur = T & 1;

        if (role == 0) {
            if (T < SS) {
                const int ph = T & 7, cb = (T >> 3) & 1;
                if ((T & 7) == 0 && T + 8 < SS) {
                    const float4 vA = *(const float4*)(rowA + (size_t)(T + 8 + st) * HH + 4 * m32);
                    const float4 vB = *(const float4*)(rowB + (size_t)(T + 8 + st) * HH + 4 * m32);
                    *(float4*)(&stg[cb ^ 1][st][0][spw]) = vA;
                    *(float4*)(&stg[cb ^ 1][st][1][spw]) = vB;
                }
                // own-h fragments, both batches
                const v2f* hbA = (const v2f*)&hsw[0][0][cur][12 * r];
                const v2f* hbB = (const v2f*)&hsw[0][1][cur][12 * r];
                const v2f yA0 = hbA[0], yA1 = hbA[1], yA2 = hbA[2], yA3 = hbA[3];
                const v2f yB0 = hbB[0], yB1 = hbB[1], yB2 = hbB[2], yB3 = hbB[3];
                float vA[8], vB[8], zA, zB;
                if (PAIR == 0) {
                    #define M0(i) MAC4(i, yA0, yA1, yA2, yA3, vA[i]) \
                                  MAC4(i, yB0, yB1, yB2, yB3, vB[i])
                    FORSLOT(M0)
                    #undef M0
                    zA = stg[cb][ph][0][wsw] + bias + red_scatter(vA, r);
                    zB = stg[cb][ph][1][wsw] + bias + red_scatter(vB, r);
                } else {
                    const v2f* sxA = (const v2f*)&stg[cb][ph][0][12 * r];
                    const v2f* sxB = (const v2f*)&stg[cb][ph][1][12 * r];
                    const v2f xA0 = sxA[0], xA1 = sxA[1], xA2 = sxA[2], xA3 = sxA[3];
                    const v2f xB0 = sxB[0], xB1 = sxB[1], xB2 = sxB[2], xB3 = sxB[3];
                    #define M1(i) MAC8(i, xA0, xA1, xA2, xA3, yA0, yA1, yA2, yA3, vA[i]) \
                                  MAC8(i, xB0, xB1, xB2, xB3, yB0, yB1, yB2, yB3, vB[i])
                    FORSLOT(M1)
                    #undef M1
                    zA = bias + red_scatter(vA, r);
                    zB = bias + red_scatter(vB, r);
                }
                const float nA = tanh_fast(zA);
                const float nB = tanh_fast(zB);
                if (r < 8) {
                    hsw[0][0][cur ^ 1][wsw] = nA;
                    hsw[0][1][cur ^ 1][wsw] = nB;
                }
            }
        } else {
            if (T >= 1) {
                const v2f* hxA = (const v2f*)&hsw[0][0][cur][12 * r];
                const v2f* hxB = (const v2f*)&hsw[0][1][cur][12 * r];
                const v2f* hyA = (const v2f*)&hsw[1][0][cur][12 * r];
                const v2f* hyB = (const v2f*)&hsw[1][1][cur][12 * r];
                const v2f xA0 = hxA[0], xA1 = hxA[1], xA2 = hxA[2], xA3 = hxA[3];
                const v2f xB0 = hxB[0], xB1 = hxB[1], xB2 = hxB[2], xB3 = hxB[3];
                const v2f yA0 = hyA[0], yA1 = hyA[1], yA2 = hyA[2], yA3 = hyA[3];
                const v2f yB0 = hyB[0], yB1 = hyB[1], yB2 = hyB[2], yB3 = hyB[3];
                float vA[8], vB[8];
                #define M2(i) MAC8(i, xA0, xA1, xA2, xA3, yA0, yA1, yA2, yA3, vA[i]) \
                              MAC8(i, xB0, xB1, xB2, xB3, yB0, yB1, yB2, yB3, vB[i])
                FORSLOT(M2)
                #undef M2
                const float zA = bias + red_scatter(vA, r);
                const float zB = bias + red_scatter(vB, r);
                const float nA = tanh_fast(zA);
                const float nB = tanh_fast(zB);
                if (r < 8) {
                    hsw[1][0][cur ^ 1][wsw] = nA;
                    hsw[1][1][cur ^ 1][wsw] = nB;
                    if (PAIR == 0) {   // persist h1 for dispatch 2
                        rowA[(size_t)(T - 1) * HH + cc] = nA;
                        rowB[(size_t)(T - 1) * HH + cc] = nB;
                    }
                }
            }
        }
        barrier_nodrain();
        // R11: redefine every weight register each iteration — blocks
        // rematerialization of the weight loads; RA must keep them
        // resident in arch VGPRs across the loop.
        FORSLOT(KEEPX)
        FORSLOT(KEEPY)
    }

    // PAIR=1: h3(SS-1) written at T=SS into dbuf[1]
    if (PAIR == 1 && role == 1) {
        if (t256 < 32) {
            const float4 hv = *(const float4*)(&hsw[1][0][1][12 * (t256 >> 1) + 4 * (t256 & 1)]);
            *(float4*)(hfin + (size_t)(2 * blk) * HH + 4 * t256) = hv;
        } else if (t256 < 64) {
            const int t2 = t256 - 32;
            const float4 hv = *(const float4*)(&hsw[1][1][1][12 * (t2 >> 1) + 4 * (t2 & 1)]);
            *(float4*)(hfin + (size_t)(2 * blk + 1) * HH + 4 * t2) = hv;
        }
    }
}

// =====================================================================
__global__ __launch_bounds__(128)
void fc_k(const float* __restrict__ hlast, const float* __restrict__ fc_w,
          const float* __restrict__ fc_b, float* __restrict__ out)
{
    const int b = blockIdx.x;
    const int tid = threadIdx.x;
    __shared__ __align__(16) float h[HH];
    h[tid] = hlast[(size_t)b * HH + tid];
    __syncthreads();
    if (tid < NC) {
        float a = fc_b[tid];
        const float* wr = fc_w + tid * HH;
        #pragma unroll 4
        for (int k = 0; k < HH; ++k) a += h[k] * wr[k];
        out[(size_t)b * NC + tid] = a;
    }
}

extern "C" void kernel_launch(void* const* d_in, const int* in_sizes, int n_in,
                              void* d_out, int out_size, void* d_ws, size_t ws_size,
                              hipStream_t stream) {
    const float* x     = (const float*)d_in[0];   // (512,256,28)
    const float* w_ih0 = (const float*)d_in[1];   // (128,28)
    const float* w_hh0 = (const float*)d_in[2];   // (128,128)
    const float* b_ih0 = (const float*)d_in[3];
    const float* b_hh0 = (const float*)d_in[4];
    const float* w_ih  = (const float*)d_in[5];   // (3,128,128): layers 1..3 input proj
    const float* w_hh  = (const float*)d_in[6];   // (3,128,128): layers 1..3 recurrent
    const float* b_ih  = (const float*)d_in[7];   // (3,128)
    const float* b_hh  = (const float*)d_in[8];
    const float* fc_w  = (const float*)d_in[9];   // (10,128)
    const float* fc_b  = (const float*)d_in[10];
    float* out = (float*)d_out;

    float* buf  = (float*)d_ws;                   // (B,S,H) fp32 = 64 MB
    float* hfin = buf + (size_t)BB * SS * HH;     // (B,H)

    // layer 0 input projection (bias-free; scans add bias)
    proj_k<28><<<(BB * SS) / 64, 256, 0, stream>>>(x, w_ih0, buf);
    // layers 0+1: role0 = layer0 rec (staged xw0), role1 = layer1
    // combined-K (writes h1 rows into buf)
    scan_fuse<0><<<BB / 2, 512, 0, stream>>>(
        buf, hfin,
        w_hh0, nullptr,
        w_ih, w_hh,                                  // layer 1: W_ih1, W_hh1
        b_ih0, b_hh0, b_ih, b_hh);
    // layers 2+3: role0 = layer2 combined-K (x-half = staged h1 rows),
    // role1 = layer3 combined-K (writes final h)
    scan_fuse<1><<<BB / 2, 512, 0, stream>>>(
        buf, hfin,
        w_ih + (size_t)1 * HH * HH, w_hh + (size_t)1 * HH * HH,  // layer 2
        w_ih + (size_t)2 * HH * HH, w_hh + (size_t)2 * HH * HH,  // layer 3
        b_ih + HH, b_hh + HH, b_ih + 2 * HH, b_hh + 2 * HH);
    fc_k<<<BB, 128, 0, stream>>>(hfin, fc_w, fc_b, out);
}

// Round 12
// 544.936 us; speedup vs baseline: 1.0611x; 1.0611x over previous
//
#include <hip/hip_runtime.h>

#define BB 512
#define SS 256
#define HH 128
#define NC 10

typedef float v2f __attribute__((ext_vector_type(2)));

// acc + (give from lane selected by DPP ctrl)
template<int CTRL>
__device__ __forceinline__ float dppadd(float acc, float give) {
    int t = __builtin_amdgcn_update_dpp(0, __float_as_int(give), CTRL, 0xF, 0xF, true);
    return acc + __int_as_float(t);
}

// cndmask-free reduce-scatter over the 16-lane group (verified).
// Input v[8] in permuted slot order (slot i = column 8j + (i^(r&7))).
// Returns full sum for column 8j + (r&7); copies at lanes r and r^8.
__device__ __forceinline__ float red_scatter(const float v[8], int r) {
    float s0 = dppadd<0xB1>(v[0], v[1]);    // xor1
    float s2 = dppadd<0xB1>(v[2], v[3]);
    float s4 = dppadd<0xB1>(v[4], v[5]);
    float s6 = dppadd<0xB1>(v[6], v[7]);
    s0 = dppadd<0x4E>(s0, s2);              // xor2
    s4 = dppadd<0x4E>(s4, s6);
    {   // xor4 via row_ror 4 / 12
        int t1 = __builtin_amdgcn_update_dpp(0, __float_as_int(s4), 0x124, 0xF, 0xF, true);
        int t2 = __builtin_amdgcn_update_dpp(0, __float_as_int(s4), 0x12C, 0xF, 0xF, true);
        s0 += __int_as_float((r & 4) ? t2 : t1);
    }
    s0 = dppadd<0x128>(s0, s0);             // xor8 (row_ror:8)
    return s0;
}

// Barrier without the compiler's vmcnt(0) drain (LDS-visibility only).
__device__ __forceinline__ void barrier_nodrain() {
    asm volatile("s_waitcnt lgkmcnt(0)\n\ts_barrier" ::: "memory");
}

// K=128 MAC (4 v2f weights) + reduce-scatter. Scalar FMAs: on gfx950
// the VALU reads AGPR-resident weights at full rate for v_fma_f32 —
// forcing v_pk_fma_f32 instead costs one copy per operand and is
// issue-neutral at best (R8/R10/R11, all ~292-300us vs this 284us).
__device__ __forceinline__ float mac4_red(const float* __restrict__ hb_,
                                          const v2f w[8][8], int r) {
    const v2f* hb = (const v2f*)hb_;
    const v2f h0 = hb[0], h1 = hb[1], h2 = hb[2], h3 = hb[3];
    float v[8];
    #pragma unroll
    for (int i = 0; i < 8; ++i) {
        v2f a = h0 * w[i][0];
        a += h1 * w[i][1];
        a += h2 * w[i][2];
        a += h3 * w[i][3];
        v[i] = a.x + a.y;
    }
    return red_scatter(v, r);
}

// K=256 concatenated MAC: x-half (W_ih part) + y-half (W_hh part).
__device__ __forceinline__ float mac8_red(const float* __restrict__ xb_,
                                          const float* __restrict__ yb_,
                                          const v2f w[8][8], int r) {
    const v2f* xb = (const v2f*)xb_;
    const v2f* yb = (const v2f*)yb_;
    const v2f x0 = xb[0], x1 = xb[1], x2 = xb[2], x3 = xb[3];
    const v2f y0 = yb[0], y1 = yb[1], y2 = yb[2], y3 = yb[3];
    float v[8];
    #pragma unroll
    for (int i = 0; i < 8; ++i) {
        v2f a = x0 * w[i][0];
        a += x1 * w[i][1];
        a += x2 * w[i][2];
        a += x3 * w[i][3];
        a += y0 * w[i][4];
        a += y1 * w[i][5];
        a += y2 * w[i][6];
        a += y3 * w[i][7];
        v[i] = a.x + a.y;
    }
    return red_scatter(v, r);
}

__device__ __forceinline__ float tanh_fast(float z) {
    const float e = __expf(2.f * z);
    return 1.f - 2.f * __builtin_amdgcn_rcpf(1.f + e);
}

// =====================================================================
// proj_k: out[m][j] = sum_d A[m][d] * W[j][d]   (NO bias — scans add it)
// Layer 0 input projection only (K=28).  (Proven kernel, unchanged.)
// =====================================================================
template<int K>
__global__ __launch_bounds__(256, 1)
void proj_k(const float* __restrict__ A, const float* __restrict__ W,
            float* __restrict__ out)
{
    constexpr int AS = ((K + 31) / 32) * 32 + 4;
    constexpr int KQ = K / 4;
    constexpr int KCW = (K < 32) ? K : 32;
    constexpr int WQ = KCW / 4;
    const int tid = threadIdx.x;
    const int tx = tid & 15;
    const int ty = tid >> 4;
    const size_t m0 = (size_t)blockIdx.x * 64;

    __shared__ float Arm[64 * AS];
    __shared__ float Wst[128 * 36];

    for (int idx = tid; idx < 64 * KQ; idx += 256) {
        const int row = idx / KQ, kq = idx % KQ;
        const float4 v = *(const float4*)(A + (m0 + row) * K + 4 * kq);
        *(float4*)(&Arm[row * AS + 4 * kq]) = v;
    }

    float acc[4][8];
    #pragma unroll
    for (int c = 0; c < 8; ++c)
        #pragma unroll
        for (int r = 0; r < 4; ++r) acc[r][c] = 0.f;

    #pragma unroll 1
    for (int kc = 0; kc < K; kc += KCW) {
        __syncthreads();
        for (int idx = tid; idx < 128 * WQ; idx += 256) {
            const int col = idx / WQ, q = idx % WQ;
            const float4 v = *(const float4*)(W + (size_t)col * K + kc + 4 * q);
            *(float4*)(&Wst[col * 36 + 4 * q]) = v;
        }
        __syncthreads();
        #pragma unroll 2
        for (int q = 0; q < WQ; ++q) {
            float4 av[4];
            #pragma unroll
            for (int r = 0; r < 4; ++r)
                av[r] = *(const float4*)(&Arm[(ty + 16 * r) * AS + kc + 4 * q]);
            #pragma unroll
            for (int c = 0; c < 8; ++c) {
                const float4 wv = *(const float4*)(&Wst[(tx + 16 * c) * 36 + 4 * q]);
                #pragma unroll
                for (int r = 0; r < 4; ++r)
                    acc[r][c] += av[r].x * wv.x + av[r].y * wv.y
                               + av[r].z * wv.z + av[r].w * wv.w;
            }
        }
    }

    #pragma unroll
    for (int r = 0; r < 4; ++r)
        #pragma unroll
        for (int c = 0; c < 8; ++c)
            out[(m0 + ty + 16 * r) * HH + tx + 16 * c] = acc[r][c];
}

// =====================================================================
// scan_fuse<PAIR>: TWO stacked layers via combined-K recurrence, 2
// batches per block, 512 threads = role0 (layer 2*PAIR) + role1 (layer
// 2*PAIR+1). Projection fused into the next layer's recurrence as one
// K=256 MAC: h_B(s) = tanh(b + [h_A(s) ‖ h_B(s-1)] @ [W_ih ‖ W_hh]^T).
//   PAIR=0: role0 = layer0 (staged xw0 + K=128 W_hh0);
//           role1 = layer1 (K=256), writes h1 rows to buf (plain).
//   PAIR=1: role0 = layer2 (K=256, x-half = STAGED h1 rows);
//           role1 = layer3 (K=256), final h -> hfin.
// This is the session's measured optimum (R7: 541.4 us total) — at
// ~73% of the scalar-FMA roofline (15.5 G-MAC / 39.3 T-MAC/s = 394 us
// floor; reduce+tanh+staging overhead accounts for the rest). The 2x
// packed path is RA-blocked (R8/R10/R11); MFMA is LDS-BW-bound (R9);
// TLP is step-wall-invariant (R0-R5).
// =====================================================================
template<int PAIR>
__global__ __attribute__((amdgpu_flat_work_group_size(512, 512),
                          amdgpu_waves_per_eu(2, 2)))
void scan_fuse(float* __restrict__ buf, float* __restrict__ hfin,
               const float* __restrict__ w_r0_a, const float* __restrict__ w_r0_b,
               const float* __restrict__ w_r1_a, const float* __restrict__ w_r1_b,
               const float* __restrict__ b0_ih, const float* __restrict__ b0_hh,
               const float* __restrict__ b1_ih, const float* __restrict__ b1_hh)
{
    const int blk  = blockIdx.x;
    const int tid  = threadIdx.x;
    const int role = tid >> 8;       // 0 = layer A, 1 = layer B (combined-K)
    const int t256 = tid & 255;
    const int j   = t256 >> 4;       // col group: cols 8j..8j+7
    const int r   = t256 & 15;       // k-chunk [8r, 8r+8)
    const int g7  = r & 7;
    const int cc  = 8 * j + g7;      // column this lane finalizes
    const int wsw = 12 * j + g7;     // swizzled word for cc

    float* const rowA = buf + (size_t)(2 * blk) * SS * HH;
    float* const rowB = rowA + (size_t)SS * HH;
    const float bias = role ? (b1_ih[cc] + b1_hh[cc]) : (b0_ih[cc] + b0_hh[cc]);

    // permuted weights: slot i = column 8j + (i^g7); [0..3] = x-half
    // (W_ih or W_hh0), [4..7] = y-half (W_hh) for combined-K roles.
    const float* wa = role ? w_r1_a : w_r0_a;
    const float* wb = role ? w_r1_b : w_r0_b;
    v2f w[8][8];
    #pragma unroll
    for (int i = 0; i < 8; ++i) {
        const size_t col = (size_t)(8 * j + (i ^ g7));
        const v2f* pa = (const v2f*)(wa + col * HH + 8 * r);
        w[i][0] = pa[0]; w[i][1] = pa[1]; w[i][2] = pa[2]; w[i][3] = pa[3];
        if (PAIR == 1 || role == 1) {
            const v2f* pb = (const v2f*)(wb + col * HH + 8 * r);
            w[i][4] = pb[0]; w[i][5] = pb[1]; w[i][6] = pb[2]; w[i][7] = pb[3];
        }
    }

    __shared__ float hsw[2][2][2][192];   // [layer][batch][dbuf][192], swizzled
    __shared__ float stg[2][8][2][192];   // [chunk][step][batch][192], swizzled

    for (int i = tid; i < 2 * 2 * 2 * 192; i += 512) ((float*)hsw)[i] = 0.f;

    const int st  = t256 >> 5;            // staging: step-in-chunk
    const int m32 = t256 & 31;            // staging: float4 index in row
    const int spw = 12 * (m32 >> 1) + 4 * (m32 & 1);  // swizzled float4 word
    if (role == 0) {                      // stage rows 0..7 (xw0 or h1)
        const float4 vA = *(const float4*)(rowA + (size_t)st * HH + 4 * m32);
        const float4 vB = *(const float4*)(rowB + (size_t)st * HH + 4 * m32);
        *(float4*)(&stg[0][st][0][spw]) = vA;
        *(float4*)(&stg[0][st][1][spw]) = vB;
    }
    __syncthreads();

    for (int T = 0; T <= SS; ++T) {
        const int cur = T & 1;

        if (role == 0) {
            if (T < SS) {
                const int ph = T & 7, cb = (T >> 3) & 1;
                if ((T & 7) == 0 && T + 8 < SS) {
                    const float4 vA = *(const float4*)(rowA + (size_t)(T + 8 + st) * HH + 4 * m32);
                    const float4 vB = *(const float4*)(rowB + (size_t)(T + 8 + st) * HH + 4 * m32);
                    *(float4*)(&stg[cb ^ 1][st][0][spw]) = vA;
                    *(float4*)(&stg[cb ^ 1][st][1][spw]) = vB;
                }
                float zA, zB;
                if (PAIR == 0) {
                    zA = stg[cb][ph][0][wsw] + bias
                       + mac4_red(&hsw[0][0][cur][12 * r], w, r);
                    zB = stg[cb][ph][1][wsw] + bias
                       + mac4_red(&hsw[0][1][cur][12 * r], w, r);
                } else {
                    zA = bias + mac8_red(&stg[cb][ph][0][12 * r],
                                         &hsw[0][0][cur][12 * r], w, r);
                    zB = bias + mac8_red(&stg[cb][ph][1][12 * r],
                                         &hsw[0][1][cur][12 * r], w, r);
                }
                const float nA = tanh_fast(zA);
                const float nB = tanh_fast(zB);
                if (r < 8) {
                    hsw[0][0][cur ^ 1][wsw] = nA;
                    hsw[0][1][cur ^ 1][wsw] = nB;
                }
            }
        } else {
            if (T >= 1) {
                const float zA = bias + mac8_red(&hsw[0][0][cur][12 * r],
                                                 &hsw[1][0][cur][12 * r], w, r);
                const float zB = bias + mac8_red(&hsw[0][1][cur][12 * r],
                                                 &hsw[1][1][cur][12 * r], w, r);
                const float nA = tanh_fast(zA);
                const float nB = tanh_fast(zB);
                if (r < 8) {
                    hsw[1][0][cur ^ 1][wsw] = nA;
                    hsw[1][1][cur ^ 1][wsw] = nB;
                    if (PAIR == 0) {   // persist h1 for dispatch 2
                        rowA[(size_t)(T - 1) * HH + cc] = nA;
                        rowB[(size_t)(T - 1) * HH + cc] = nB;
                    }
                }
            }
        }
        barrier_nodrain();
    }

    // PAIR=1: h3(SS-1) written at T=SS into dbuf[1]
    if (PAIR == 1 && role == 1) {
        if (t256 < 32) {
            const float4 hv = *(const float4*)(&hsw[1][0][1][12 * (t256 >> 1) + 4 * (t256 & 1)]);
            *(float4*)(hfin + (size_t)(2 * blk) * HH + 4 * t256) = hv;
        } else if (t256 < 64) {
            const int t2 = t256 - 32;
            const float4 hv = *(const float4*)(&hsw[1][1][1][12 * (t2 >> 1) + 4 * (t2 & 1)]);
            *(float4*)(hfin + (size_t)(2 * blk + 1) * HH + 4 * t2) = hv;
        }
    }
}

// =====================================================================
__global__ __launch_bounds__(128)
void fc_k(const float* __restrict__ hlast, const float* __restrict__ fc_w,
          const float* __restrict__ fc_b, float* __restrict__ out)
{
    const int b = blockIdx.x;
    const int tid = threadIdx.x;
    __shared__ __align__(16) float h[HH];
    h[tid] = hlast[(size_t)b * HH + tid];
    __syncthreads();
    if (tid < NC) {
        float a = fc_b[tid];
        const float* wr = fc_w + tid * HH;
        #pragma unroll 4
        for (int k = 0; k < HH; ++k) a += h[k] * wr[k];
        out[(size_t)b * NC + tid] = a;
    }
}

extern "C" void kernel_launch(void* const* d_in, const int* in_sizes, int n_in,
                              void* d_out, int out_size, void* d_ws, size_t ws_size,
                              hipStream_t stream) {
    const float* x     = (const float*)d_in[0];   // (512,256,28)
    const float* w_ih0 = (const float*)d_in[1];   // (128,28)
    const float* w_hh0 = (const float*)d_in[2];   // (128,128)
    const float* b_ih0 = (const float*)d_in[3];
    const float* b_hh0 = (const float*)d_in[4];
    const float* w_ih  = (const float*)d_in[5];   // (3,128,128): layers 1..3 input proj
    const float* w_hh  = (const float*)d_in[6];   // (3,128,128): layers 1..3 recurrent
    const float* b_ih  = (const float*)d_in[7];   // (3,128)
    const float* b_hh  = (const float*)d_in[8];
    const float* fc_w  = (const float*)d_in[9];   // (10,128)
    const float* fc_b  = (const float*)d_in[10];
    float* out = (float*)d_out;

    float* buf  = (float*)d_ws;                   // (B,S,H) fp32 = 64 MB
    float* hfin = buf + (size_t)BB * SS * HH;     // (B,H)

    // layer 0 input projection (bias-free; scans add bias)
    proj_k<28><<<(BB * SS) / 64, 256, 0, stream>>>(x, w_ih0, buf);
    // layers 0+1: role0 = layer0 rec (staged xw0), role1 = layer1
    // combined-K (writes h1 rows into buf)
    scan_fuse<0><<<BB / 2, 512, 0, stream>>>(
        buf, hfin,
        w_hh0, nullptr,
        w_ih, w_hh,                                  // layer 1: W_ih1, W_hh1
        b_ih0, b_hh0, b_ih, b_hh);
    // layers 2+3: role0 = layer2 combined-K (x-half = staged h1 rows),
    // role1 = layer3 combined-K (writes final h)
    scan_fuse<1><<<BB / 2, 512, 0, stream>>>(
        buf, hfin,
        w_ih + (size_t)1 * HH * HH, w_hh + (size_t)1 * HH * HH,  // layer 2
        w_ih + (size_t)2 * HH * HH, w_hh + (size_t)2 * HH * HH,  // layer 3
        b_ih + HH, b_hh + HH, b_ih + 2 * HH, b_hh + 2 * HH);
    fc_k<<<BB, 128, 0, stream>>>(hfin, fc_w, fc_b, out);
}